// Round 12
// baseline (182.190 us; speedup 1.0000x reference)
//
#include <hip/hip_runtime.h>
#include <hip/hip_bf16.h>

#define HIDDEN 256
#define NB 4            // batches
#define NQ 200          // queries
#define MT 13           // m-tiles of 16 (208 padded rows)
#define HW 65536        // 256*256 pixels
#define KSTEPS 8        // 256 / 32
#define NPB 64          // pixels per gemm tile
#define NTILE 16        // tiles per persistent block
#define GT 512          // gemm threads (8 waves)
#define HBB 16384       // half-panel bytes: 64 n x 128 k bf16
#define ABYTES (MT * KSTEPS * 1024)          // 106496: A frags in LDS
#define SMEM_TOTAL (ABYTES + 3 * HBB)        // 155648 <= 160 KB

typedef __attribute__((ext_vector_type(8))) __bf16 bf16x8;
typedef __attribute__((ext_vector_type(4))) float f32x4;

#define WAITVM0()    asm volatile("s_waitcnt vmcnt(0)" ::: "memory")
#define WAIT_LGKM0() asm volatile("s_waitcnt lgkmcnt(0)" ::: "memory")
__device__ __forceinline__ void hard_barrier() {
    __builtin_amdgcn_sched_barrier(0);
    __builtin_amdgcn_s_barrier();
    __builtin_amdgcn_sched_barrier(0);
}

// async global->LDS, 16 B per lane; LDS dest = wave-uniform base + lane*16
__device__ __forceinline__ void gload_lds16(const void* g, void* l) {
    __builtin_amdgcn_global_load_lds(
        (const __attribute__((address_space(1))) void*)g,
        (__attribute__((address_space(3))) void*)l, 16, 0, 0);
}

// ---------------------------------------------------------------------------
// Kernel 1: mask_embed MLP -> bf16 A-fragments in d_ws (unchanged, verified).
// A_ws layout: [b][mt][ks][lane(64)][j(8)] bf16,
//   element (row = mt*16 + (lane&15), k = ks*32 + (lane>>4)*8 + j)
// ---------------------------------------------------------------------------
__global__ __launch_bounds__(1024)
void mlp_pack(const float* __restrict__ queries,
              const float* __restrict__ w1, const float* __restrict__ b1,
              const float* __restrict__ w2, const float* __restrict__ b2,
              __bf16* __restrict__ A_ws)
{
    __shared__ float qh[16][HIDDEN];
    __shared__ float wb[HIDDEN][33];
    const int blk = blockIdx.x;
    const int b = blk / MT, mt = blk % MT;
    const int tid = threadIdx.x;

    for (int idx = tid; idx < 16 * HIDDEN; idx += 1024) {
        int r = idx >> 8, c = idx & 255;
        int q = mt * 16 + r;
        qh[r][c] = (q < NQ) ? queries[((size_t)b * NQ + q) * HIDDEN + c] : 0.f;
    }
    __syncthreads();

    const int t  = tid & 255;
    const int rq = tid >> 8;
    const int sr = tid >> 2;
    const int si = tid & 3;

    float h[4];
    #pragma unroll
    for (int r = 0; r < 4; ++r) h[r] = b1[t];
    for (int cc = 0; cc < 8; ++cc) {
        const float* src = w1 + (size_t)sr * HIDDEN + cc * 32;
        float4 va = *reinterpret_cast<const float4*>(src + si * 4);
        float4 vb = *reinterpret_cast<const float4*>(src + 16 + si * 4);
        wb[sr][si*4+0] = va.x; wb[sr][si*4+1] = va.y;
        wb[sr][si*4+2] = va.z; wb[sr][si*4+3] = va.w;
        wb[sr][16+si*4+0] = vb.x; wb[sr][16+si*4+1] = vb.y;
        wb[sr][16+si*4+2] = vb.z; wb[sr][16+si*4+3] = vb.w;
        __syncthreads();
        #pragma unroll
        for (int cl = 0; cl < 32; ++cl) {
            float w = wb[t][cl];
            #pragma unroll
            for (int r = 0; r < 4; ++r)
                h[r] = fmaf(qh[rq * 4 + r][cc * 32 + cl], w, h[r]);
        }
        __syncthreads();
    }

    #pragma unroll
    for (int r = 0; r < 4; ++r) qh[rq * 4 + r][t] = fmaxf(h[r], 0.f);
    __syncthreads();

    float me[4];
    #pragma unroll
    for (int r = 0; r < 4; ++r) me[r] = b2[t];
    for (int cc = 0; cc < 8; ++cc) {
        const float* src = w2 + (size_t)sr * HIDDEN + cc * 32;
        float4 va = *reinterpret_cast<const float4*>(src + si * 4);
        float4 vb = *reinterpret_cast<const float4*>(src + 16 + si * 4);
        wb[sr][si*4+0] = va.x; wb[sr][si*4+1] = va.y;
        wb[sr][si*4+2] = va.z; wb[sr][si*4+3] = va.w;
        wb[sr][16+si*4+0] = vb.x; wb[sr][16+si*4+1] = vb.y;
        wb[sr][16+si*4+2] = vb.z; wb[sr][16+si*4+3] = vb.w;
        __syncthreads();
        #pragma unroll
        for (int cl = 0; cl < 32; ++cl) {
            float w = wb[t][cl];
            #pragma unroll
            for (int r = 0; r < 4; ++r)
                me[r] = fmaf(qh[rq * 4 + r][cc * 32 + cl], w, me[r]);
        }
        __syncthreads();
    }

    const int ks = t >> 5, g = (t >> 3) & 3, j = t & 7;
    #pragma unroll
    for (int r = 0; r < 4; ++r) {
        int row = rq * 4 + r;
        int q = mt * 16 + row;
        float v = (q < NQ) ? me[r] : 0.f;
        int lane = row + 16 * g;
        size_t addr = ((size_t)((b * MT + mt) * KSTEPS + ks)) * 512 + (size_t)lane * 8 + j;
        A_ws[addr] = (__bf16)v;
    }
}

// ---------------------------------------------------------------------------
// Kernel 2 v11: ring pipeline (r11) + barrier-free DIRECT-STORE epilogue.
// 256 blocks (1/CU), 512 thr / 8 waves, 152 KB LDS:
//   [A frags 104 KB (staged once via gload_lds)] [3 x 16 KB B half-panels]
// Wave wv owns m-tiles {wv, wv+8}; acc[2][4] = 32 regs; staging v[16].
// Slot s (= tile s>>1, k-half s&1), buffers rotate s%3:
//   issue 16 reads for slot s+1 -> compute 4 ksteps (pure LDS+MFMA) ->
//   ds_write slot s+1 (counted vmcnt on v, inserted by compiler) ->
//   [odd slot: DIRECT stores from acc -- 32 predicated dword stores/wave,
//    4x64B segments/instr; adjacent f's merge into full L2 lines; ZERO
//    barriers (r11's LDS-transpose epilogue cost 14 barriers/tile = ~16us)]
//   -> lgkm wait + barrier (ring correctness, 1 per slot).
// B half-panel layout: elem (n,k): byte n*256 + (((k>>3) ^ (n&7))<<4) + (k&7)*2
// ---------------------------------------------------------------------------
__global__ __launch_bounds__(GT)
void mask_gemm(const float* __restrict__ mf,
               const __bf16* __restrict__ A_ws,
               float* __restrict__ out)
{
    extern __shared__ char smem[];
    char* Ar = smem;                   // A fragment region
    char* HB = smem + ABYTES;          // 3 half-panel buffers

    const int bid = blockIdx.x;
    const int b   = bid >> 6;                      // 64 blocks per batch
    const int px0 = (bid & 63) * (NTILE * NPB);    // 1024-px contiguous span
    const int tid = threadIdx.x;
    const int ln  = tid & 63, wv = tid >> 6;
    const int l15 = ln & 15,  lg = ln >> 4;
    const bool has2 = (wv + 8) < MT;
    const int sn = ln;                 // staging: n within tile
    const int su = wv;                 // staging: unit pair index

    const float*  mfB  = mf  + (size_t)b * HIDDEN * HW;
    const __bf16* Ab   = A_ws + (size_t)b * (MT * KSTEPS * 512);
    float*        outB = out + (size_t)b * NQ * HW;

    // ---- stage A panel into LDS (once): 13 frags per wave, lane-linear ----
    for (int fi = wv; fi < MT * KSTEPS; fi += 8)
        gload_lds16(Ab + (size_t)fi * 512 + (size_t)ln * 8,
                    Ar + fi * 1024 + ln * 16);

    // ---- slot 0 reads ----
    float v[16];
    {
        const float* src = mfB + px0 + sn;          // tile 0, half 0
        #pragma unroll
        for (int c = 0; c < 2; ++c)
            #pragma unroll
            for (int j = 0; j < 8; ++j)
                v[c * 8 + j] = src[(size_t)((su * 2 + c) * 8 + j) * HW];
    }
    WAITVM0();                          // A gloads + slot-0 reads complete
    #pragma unroll
    for (int c = 0; c < 2; ++c) {
        bf16x8 pk;
        #pragma unroll
        for (int j = 0; j < 8; ++j) pk[j] = (__bf16)v[c * 8 + j];
        const int u = su * 2 + c;
        *reinterpret_cast<bf16x8*>(HB + sn * 256 + ((u ^ (sn & 7)) << 4)) = pk;
    }
    WAIT_LGKM0();
    hard_barrier();

    f32x4 acc[2][4];
    #pragma unroll
    for (int ii = 0; ii < 2; ++ii)
        #pragma unroll
        for (int f = 0; f < 4; ++f) acc[ii][f] = (f32x4){0.f, 0.f, 0.f, 0.f};

    // ---- slot loop: 32 slots = 16 tiles x 2 k-halves ----
    for (int s = 0; s < 2 * NTILE; ++s) {
        const int i = s >> 1, h = s & 1;
        char* bcur = HB + (s % 3) * HBB;
        const bool hn = (s + 1) < 2 * NTILE;

        // issue reads for slot s+1 (fly through compute)
        if (hn) {
            const int i2 = (s + 1) >> 1, h2 = (s + 1) & 1;
            const float* src = mfB + (size_t)h2 * 128 * HW + px0 + i2 * NPB + sn;
            #pragma unroll
            for (int c = 0; c < 2; ++c)
                #pragma unroll
                for (int j = 0; j < 8; ++j)
                    v[c * 8 + j] = src[(size_t)((su * 2 + c) * 8 + j) * HW];
            __builtin_amdgcn_sched_barrier(0);   // pin issuance before K-loop
        }

        // compute 4 ksteps from bcur (pure LDS + MFMA, zero vmem)
        #pragma unroll
        for (int kk = 0; kk < 4; ++kk) {
            const int t = h * 4 + kk;
            bf16x8 a0 = *reinterpret_cast<const bf16x8*>(
                Ar + (wv * KSTEPS + t) * 1024 + ln * 16);
            bf16x8 a1;
            if (has2)
                a1 = *reinterpret_cast<const bf16x8*>(
                    Ar + ((wv + 8) * KSTEPS + t) * 1024 + ln * 16);
            #pragma unroll
            for (int f = 0; f < 4; ++f) {
                bf16x8 bf = *reinterpret_cast<const bf16x8*>(
                    bcur + (f * 16 + l15) * 256 + (((kk * 4 + lg) ^ (l15 & 7)) << 4));
                acc[0][f] = __builtin_amdgcn_mfma_f32_16x16x32_bf16(
                    a0, bf, acc[0][f], 0, 0, 0);
                if (has2)
                    acc[1][f] = __builtin_amdgcn_mfma_f32_16x16x32_bf16(
                        a1, bf, acc[1][f], 0, 0, 0);
            }
        }

        // ds_write slot s+1 into its ring buffer (not referenced this slot);
        // compiler inserts the counted vmcnt wait for v's loads only.
        if (hn) {
            char* bnxt = HB + ((s + 1) % 3) * HBB;
            #pragma unroll
            for (int c = 0; c < 2; ++c) {
                bf16x8 pk;
                #pragma unroll
                for (int j = 0; j < 8; ++j) pk[j] = (__bf16)v[c * 8 + j];
                const int u = su * 2 + c;
                *reinterpret_cast<bf16x8*>(bnxt + sn * 256 + ((u ^ (sn & 7)) << 4)) = pk;
            }
        }

        // odd slot: tile i complete -> DIRECT stores from acc (no LDS, no bar)
        // C/D frag: col = l15 (+f*16), row = lg*4 + r within m-tile.
        if (h == 1) {
            float* outb = outB + (px0 + i * NPB) + l15;
            #pragma unroll
            for (int ii = 0; ii < 2; ++ii) {
                if (ii == 0 || has2) {
                    const int mt = wv + 8 * ii;
                    #pragma unroll
                    for (int f = 0; f < 4; ++f) {
                        #pragma unroll
                        for (int r = 0; r < 4; ++r) {
                            const int q = mt * 16 + lg * 4 + r;
                            if (q < NQ)
                                outb[(size_t)q * HW + f * 16] = acc[ii][f][r];
                        }
                    }
                }
            }
            #pragma unroll
            for (int ii = 0; ii < 2; ++ii)
                #pragma unroll
                for (int f = 0; f < 4; ++f)
                    acc[ii][f] = (f32x4){0.f, 0.f, 0.f, 0.f};
        }

        WAIT_LGKM0();
        hard_barrier();                // ds_write visible; bcur reads done
    }
}

// ---------------------------------------------------------------------------
extern "C" void kernel_launch(void* const* d_in, const int* in_sizes, int n_in,
                              void* d_out, int out_size, void* d_ws, size_t ws_size,
                              hipStream_t stream)
{
    const float* queries = (const float*)d_in[0];
    const float* mf      = (const float*)d_in[1];
    const float* w1      = (const float*)d_in[2];
    const float* b1      = (const float*)d_in[3];
    const float* w2      = (const float*)d_in[4];
    const float* b2      = (const float*)d_in[5];
    float*  out  = (float*)d_out;
    __bf16* A_ws = (__bf16*)d_ws;   // 4*13*8*512*2 = 425,984 B

    (void)hipFuncSetAttribute((const void*)mask_gemm,
                              hipFuncAttributeMaxDynamicSharedMemorySize,
                              SMEM_TOTAL);

    hipLaunchKernelGGL(mlp_pack, dim3(NB * MT), dim3(1024), 0, stream,
                       queries, w1, b1, w2, b2, A_ws);
    hipLaunchKernelGGL(mask_gemm, dim3(256), dim3(GT), SMEM_TOTAL, stream,
                       mf, A_ws, out);
}

// Round 13
// 131.416 us; speedup vs baseline: 1.3864x; 1.3864x over previous
//
#include <hip/hip_runtime.h>
#include <hip/hip_bf16.h>

#define HIDDEN 256
#define NB 4            // batches
#define NQ 200          // queries
#define MT 13           // m-tiles of 16 (208 padded rows)
#define HW 65536        // 256*256 pixels
#define KSTEPS 8        // 256 / 32
#define NPB 64          // pixels per gemm tile
#define NTILE 16        // tiles per persistent block
#define GT 512          // gemm threads (8 waves)
#define HBB 16384       // half-panel bytes: 64 n x 128 k bf16
#define ABYTES (MT * KSTEPS * 1024)          // 106496: A frags in LDS
#define SMEM_TOTAL (ABYTES + 3 * HBB)        // 155648 <= 160 KB

typedef __attribute__((ext_vector_type(8))) __bf16 bf16x8;
typedef __attribute__((ext_vector_type(4))) float f32x4;

#define WAITVM0()    asm volatile("s_waitcnt vmcnt(0)" ::: "memory")
#define WAIT_LGKM0() asm volatile("s_waitcnt lgkmcnt(0)" ::: "memory")
__device__ __forceinline__ void hard_barrier() {
    __builtin_amdgcn_sched_barrier(0);
    __builtin_amdgcn_s_barrier();
    __builtin_amdgcn_sched_barrier(0);
}

// async global->LDS, 16 B per lane; LDS dest = wave-uniform base + lane*16
__device__ __forceinline__ void gload_lds16(const void* g, void* l) {
    __builtin_amdgcn_global_load_lds(
        (const __attribute__((address_space(1))) void*)g,
        (__attribute__((address_space(3))) void*)l, 16, 0, 0);
}

// ---------------------------------------------------------------------------
// Kernel 1: mask_embed MLP -> bf16 A-fragments in d_ws (unchanged, verified).
// A_ws layout: [b][mt][ks][lane(64)][j(8)] bf16,
//   element (row = mt*16 + (lane&15), k = ks*32 + (lane>>4)*8 + j)
// ---------------------------------------------------------------------------
__global__ __launch_bounds__(1024)
void mlp_pack(const float* __restrict__ queries,
              const float* __restrict__ w1, const float* __restrict__ b1,
              const float* __restrict__ w2, const float* __restrict__ b2,
              __bf16* __restrict__ A_ws)
{
    __shared__ float qh[16][HIDDEN];
    __shared__ float wb[HIDDEN][33];
    const int blk = blockIdx.x;
    const int b = blk / MT, mt = blk % MT;
    const int tid = threadIdx.x;

    for (int idx = tid; idx < 16 * HIDDEN; idx += 1024) {
        int r = idx >> 8, c = idx & 255;
        int q = mt * 16 + r;
        qh[r][c] = (q < NQ) ? queries[((size_t)b * NQ + q) * HIDDEN + c] : 0.f;
    }
    __syncthreads();

    const int t  = tid & 255;
    const int rq = tid >> 8;
    const int sr = tid >> 2;
    const int si = tid & 3;

    float h[4];
    #pragma unroll
    for (int r = 0; r < 4; ++r) h[r] = b1[t];
    for (int cc = 0; cc < 8; ++cc) {
        const float* src = w1 + (size_t)sr * HIDDEN + cc * 32;
        float4 va = *reinterpret_cast<const float4*>(src + si * 4);
        float4 vb = *reinterpret_cast<const float4*>(src + 16 + si * 4);
        wb[sr][si*4+0] = va.x; wb[sr][si*4+1] = va.y;
        wb[sr][si*4+2] = va.z; wb[sr][si*4+3] = va.w;
        wb[sr][16+si*4+0] = vb.x; wb[sr][16+si*4+1] = vb.y;
        wb[sr][16+si*4+2] = vb.z; wb[sr][16+si*4+3] = vb.w;
        __syncthreads();
        #pragma unroll
        for (int cl = 0; cl < 32; ++cl) {
            float w = wb[t][cl];
            #pragma unroll
            for (int r = 0; r < 4; ++r)
                h[r] = fmaf(qh[rq * 4 + r][cc * 32 + cl], w, h[r]);
        }
        __syncthreads();
    }

    #pragma unroll
    for (int r = 0; r < 4; ++r) qh[rq * 4 + r][t] = fmaxf(h[r], 0.f);
    __syncthreads();

    float me[4];
    #pragma unroll
    for (int r = 0; r < 4; ++r) me[r] = b2[t];
    for (int cc = 0; cc < 8; ++cc) {
        const float* src = w2 + (size_t)sr * HIDDEN + cc * 32;
        float4 va = *reinterpret_cast<const float4*>(src + si * 4);
        float4 vb = *reinterpret_cast<const float4*>(src + 16 + si * 4);
        wb[sr][si*4+0] = va.x; wb[sr][si*4+1] = va.y;
        wb[sr][si*4+2] = va.z; wb[sr][si*4+3] = va.w;
        wb[sr][16+si*4+0] = vb.x; wb[sr][16+si*4+1] = vb.y;
        wb[sr][16+si*4+2] = vb.z; wb[sr][16+si*4+3] = vb.w;
        __syncthreads();
        #pragma unroll
        for (int cl = 0; cl < 32; ++cl) {
            float w = wb[t][cl];
            #pragma unroll
            for (int r = 0; r < 4; ++r)
                me[r] = fmaf(qh[rq * 4 + r][cc * 32 + cl], w, me[r]);
        }
        __syncthreads();
    }

    const int ks = t >> 5, g = (t >> 3) & 3, j = t & 7;
    #pragma unroll
    for (int r = 0; r < 4; ++r) {
        int row = rq * 4 + r;
        int q = mt * 16 + row;
        float v = (q < NQ) ? me[r] : 0.f;
        int lane = row + 16 * g;
        size_t addr = ((size_t)((b * MT + mt) * KSTEPS + ks)) * 512 + (size_t)lane * 8 + j;
        A_ws[addr] = (__bf16)v;
    }
}

// ---------------------------------------------------------------------------
// Kernel 2 v12: r11 ring pipeline + WAVE-PRIVATE transpose epilogue.
// 256 blocks (1/CU), 512 thr / 8 waves, 152 KB LDS:
//   [A frags 104 KB (gload_lds, once)] [3 x 16 KB B half-panel ring]
// Wave wv owns m-tiles {wv, wv+8}; acc[2][4] = 32 regs; staging v[16].
// Slot s (= tile s>>1, k-half s&1):
//   issue 16 reads(slot s+1) -> 4 ksteps (pure LDS+MFMA) -> ds_write(s+1)
//   -> [odd slot: epilogue] -> lgkm + barrier (1 per slot).
// Epilogue (NO block barriers): freed ring buffer (s+2)%3 gives each wave a
// private 2 KB scratch. Per m-tile, 4 sub-passes (sp = lg row-group):
//   lanes lg==sp: 16 conflict-free ds_write_b32 (row-major [4][64] f32)
//   -> wave-local lgkmcnt(0) -> all lanes ds_read_b128 + NT f32x4 store
//   (4 rows x 256 B contiguous per instr = r11's store shape, r12's 0 barriers)
// B half-panel layout: elem (n,k): byte n*256 + (((k>>3) ^ (n&7))<<4) + (k&7)*2
// ---------------------------------------------------------------------------
__global__ __launch_bounds__(GT)
void mask_gemm(const float* __restrict__ mf,
               const __bf16* __restrict__ A_ws,
               float* __restrict__ out)
{
    extern __shared__ char smem[];
    char* Ar = smem;                   // A fragment region
    char* HB = smem + ABYTES;          // 3 half-panel buffers

    const int bid = blockIdx.x;
    const int b   = bid >> 6;                      // 64 blocks per batch
    const int px0 = (bid & 63) * (NTILE * NPB);    // 1024-px contiguous span
    const int tid = threadIdx.x;
    const int ln  = tid & 63, wv = tid >> 6;
    const int l15 = ln & 15,  lg = ln >> 4;
    const bool has2 = (wv + 8) < MT;
    const int sn = ln;                 // staging: n within tile
    const int su = wv;                 // staging: unit pair index

    const float*  mfB  = mf  + (size_t)b * HIDDEN * HW;
    const __bf16* Ab   = A_ws + (size_t)b * (MT * KSTEPS * 512);
    float*        outB = out + (size_t)b * NQ * HW;

    // ---- stage A panel into LDS (once): 13 frags per wave, lane-linear ----
    for (int fi = wv; fi < MT * KSTEPS; fi += 8)
        gload_lds16(Ab + (size_t)fi * 512 + (size_t)ln * 8,
                    Ar + fi * 1024 + ln * 16);

    // ---- slot 0 reads ----
    float v[16];
    {
        const float* src = mfB + px0 + sn;          // tile 0, half 0
        #pragma unroll
        for (int c = 0; c < 2; ++c)
            #pragma unroll
            for (int j = 0; j < 8; ++j)
                v[c * 8 + j] = src[(size_t)((su * 2 + c) * 8 + j) * HW];
    }
    WAITVM0();                          // A gloads + slot-0 reads complete
    #pragma unroll
    for (int c = 0; c < 2; ++c) {
        bf16x8 pk;
        #pragma unroll
        for (int j = 0; j < 8; ++j) pk[j] = (__bf16)v[c * 8 + j];
        const int u = su * 2 + c;
        *reinterpret_cast<bf16x8*>(HB + sn * 256 + ((u ^ (sn & 7)) << 4)) = pk;
    }
    WAIT_LGKM0();
    hard_barrier();

    f32x4 acc[2][4];
    #pragma unroll
    for (int ii = 0; ii < 2; ++ii)
        #pragma unroll
        for (int f = 0; f < 4; ++f) acc[ii][f] = (f32x4){0.f, 0.f, 0.f, 0.f};

    // ---- slot loop: 32 slots = 16 tiles x 2 k-halves ----
    for (int s = 0; s < 2 * NTILE; ++s) {
        const int i = s >> 1, h = s & 1;
        char* bcur = HB + (s % 3) * HBB;
        const bool hn = (s + 1) < 2 * NTILE;

        // issue reads for slot s+1 (fly through compute)
        if (hn) {
            const int i2 = (s + 1) >> 1, h2 = (s + 1) & 1;
            const float* src = mfB + (size_t)h2 * 128 * HW + px0 + i2 * NPB + sn;
            #pragma unroll
            for (int c = 0; c < 2; ++c)
                #pragma unroll
                for (int j = 0; j < 8; ++j)
                    v[c * 8 + j] = src[(size_t)((su * 2 + c) * 8 + j) * HW];
            __builtin_amdgcn_sched_barrier(0);   // pin issuance before K-loop
        }

        // compute 4 ksteps from bcur (pure LDS + MFMA, zero vmem)
        #pragma unroll
        for (int kk = 0; kk < 4; ++kk) {
            const int t = h * 4 + kk;
            bf16x8 a0 = *reinterpret_cast<const bf16x8*>(
                Ar + (wv * KSTEPS + t) * 1024 + ln * 16);
            bf16x8 a1;
            if (has2)
                a1 = *reinterpret_cast<const bf16x8*>(
                    Ar + ((wv + 8) * KSTEPS + t) * 1024 + ln * 16);
            #pragma unroll
            for (int f = 0; f < 4; ++f) {
                bf16x8 bf = *reinterpret_cast<const bf16x8*>(
                    bcur + (f * 16 + l15) * 256 + (((kk * 4 + lg) ^ (l15 & 7)) << 4));
                acc[0][f] = __builtin_amdgcn_mfma_f32_16x16x32_bf16(
                    a0, bf, acc[0][f], 0, 0, 0);
                if (has2)
                    acc[1][f] = __builtin_amdgcn_mfma_f32_16x16x32_bf16(
                        a1, bf, acc[1][f], 0, 0, 0);
            }
        }

        // ds_write slot s+1 into its ring buffer (not referenced this slot);
        // compiler inserts the counted vmcnt wait for v's loads only.
        if (hn) {
            char* bnxt = HB + ((s + 1) % 3) * HBB;
            #pragma unroll
            for (int c = 0; c < 2; ++c) {
                bf16x8 pk;
                #pragma unroll
                for (int j = 0; j < 8; ++j) pk[j] = (__bf16)v[c * 8 + j];
                const int u = su * 2 + c;
                *reinterpret_cast<bf16x8*>(bnxt + sn * 256 + ((u ^ (sn & 7)) << 4)) = pk;
            }
        }

        // odd slot: tile i complete -> wave-private transpose + NT stores.
        // Scratch = freed ring buffer (s+2)%3 (= bcur of slot s-1; all reads
        // of it completed before slot s-1's ending barrier). It is not
        // written again until slot s+1's ds_write, which is after this
        // slot's ending barrier. Wave wv owns bytes [wv*2048, wv*2048+1024).
        if (h == 1) {
            float* wscr = reinterpret_cast<float*>(
                HB + ((s + 2) % 3) * HBB + wv * 2048);
            const int n0 = px0 + i * NPB;
            #pragma unroll
            for (int ii = 0; ii < 2; ++ii) {
                if (ii == 0 || has2) {
                    const int mt = wv + 8 * ii;
                    #pragma unroll
                    for (int sp = 0; sp < 4; ++sp) {
                        // write: lanes with lg == sp own rows sp*4..sp*4+3
                        if (lg == sp) {
                            #pragma unroll
                            for (int f = 0; f < 4; ++f)
                                #pragma unroll
                                for (int r = 0; r < 4; ++r)
                                    wscr[r * 64 + f * 16 + l15] = acc[ii][f][r];
                        }
                        WAIT_LGKM0();            // wave-local: writes visible
                        // read + NT store: all 64 lanes, 4 rows x 256 B
                        {
                            const int row = ln >> 4, c4 = (ln & 15) << 2;
                            f32x4 vv = *reinterpret_cast<const f32x4*>(
                                wscr + row * 64 + c4);
                            const int q = mt * 16 + sp * 4 + row;
                            if (q < NQ)
                                __builtin_nontemporal_store(vv,
                                    reinterpret_cast<f32x4*>(
                                        outB + (size_t)q * HW + n0 + c4));
                        }
                        WAIT_LGKM0();            // reads done before next sp
                    }
                }
            }
            #pragma unroll
            for (int ii = 0; ii < 2; ++ii)
                #pragma unroll
                for (int f = 0; f < 4; ++f)
                    acc[ii][f] = (f32x4){0.f, 0.f, 0.f, 0.f};
        }

        WAIT_LGKM0();
        hard_barrier();                // ds_write visible; bcur reads done
    }
}

// ---------------------------------------------------------------------------
extern "C" void kernel_launch(void* const* d_in, const int* in_sizes, int n_in,
                              void* d_out, int out_size, void* d_ws, size_t ws_size,
                              hipStream_t stream)
{
    const float* queries = (const float*)d_in[0];
    const float* mf      = (const float*)d_in[1];
    const float* w1      = (const float*)d_in[2];
    const float* b1      = (const float*)d_in[3];
    const float* w2      = (const float*)d_in[4];
    const float* b2      = (const float*)d_in[5];
    float*  out  = (float*)d_out;
    __bf16* A_ws = (__bf16*)d_ws;   // 4*13*8*512*2 = 425,984 B

    (void)hipFuncSetAttribute((const void*)mask_gemm,
                              hipFuncAttributeMaxDynamicSharedMemorySize,
                              SMEM_TOTAL);

    hipLaunchKernelGGL(mlp_pack, dim3(NB * MT), dim3(1024), 0, stream,
                       queries, w1, b1, w2, b2, A_ws);
    hipLaunchKernelGGL(mask_gemm, dim3(256), dim3(GT), SMEM_TOTAL, stream,
                       mf, A_ws, out);
}

// Round 14
// 127.317 us; speedup vs baseline: 1.4310x; 1.0322x over previous
//
#include <hip/hip_runtime.h>
#include <hip/hip_bf16.h>

#define HIDDEN 256
#define NB 4            // batches
#define NQ 200          // queries
#define MT 13           // m-tiles of 16 (208 padded rows)
#define HW 65536        // 256*256 pixels
#define KSTEPS 8        // 256 / 32
#define NPB 64          // pixels per gemm tile
#define NTILE 16        // tiles per persistent block
#define GT 512          // gemm threads (8 waves)
#define HBB 16384       // half-panel bytes: 64 n x 128 k bf16
#define ABYTES (MT * KSTEPS * 1024)          // 106496: A frags in LDS
#define SMEM_TOTAL (ABYTES + 3 * HBB)        // 155648 <= 160 KB

typedef __attribute__((ext_vector_type(8))) __bf16 bf16x8;
typedef __attribute__((ext_vector_type(4))) float f32x4;

#define WAITVM0()    asm volatile("s_waitcnt vmcnt(0)" ::: "memory")
#define WAIT_LGKM0() asm volatile("s_waitcnt lgkmcnt(0)" ::: "memory")
__device__ __forceinline__ void hard_barrier() {
    __builtin_amdgcn_sched_barrier(0);
    __builtin_amdgcn_s_barrier();
    __builtin_amdgcn_sched_barrier(0);
}

// async global->LDS, 16 B per lane; LDS dest = wave-uniform base + lane*16
__device__ __forceinline__ void gload_lds16(const void* g, void* l) {
    __builtin_amdgcn_global_load_lds(
        (const __attribute__((address_space(1))) void*)g,
        (__attribute__((address_space(3))) void*)l, 16, 0, 0);
}

// ---------------------------------------------------------------------------
// Kernel 1: mask_embed MLP -> bf16 A-fragments in d_ws (unchanged, verified).
// A_ws layout: [b][mt][ks][lane(64)][j(8)] bf16,
//   element (row = mt*16 + (lane&15), k = ks*32 + (lane>>4)*8 + j)
// ---------------------------------------------------------------------------
__global__ __launch_bounds__(1024)
void mlp_pack(const float* __restrict__ queries,
              const float* __restrict__ w1, const float* __restrict__ b1,
              const float* __restrict__ w2, const float* __restrict__ b2,
              __bf16* __restrict__ A_ws)
{
    __shared__ float qh[16][HIDDEN];
    __shared__ float wb[HIDDEN][33];
    const int blk = blockIdx.x;
    const int b = blk / MT, mt = blk % MT;
    const int tid = threadIdx.x;

    for (int idx = tid; idx < 16 * HIDDEN; idx += 1024) {
        int r = idx >> 8, c = idx & 255;
        int q = mt * 16 + r;
        qh[r][c] = (q < NQ) ? queries[((size_t)b * NQ + q) * HIDDEN + c] : 0.f;
    }
    __syncthreads();

    const int t  = tid & 255;
    const int rq = tid >> 8;
    const int sr = tid >> 2;
    const int si = tid & 3;

    float h[4];
    #pragma unroll
    for (int r = 0; r < 4; ++r) h[r] = b1[t];
    for (int cc = 0; cc < 8; ++cc) {
        const float* src = w1 + (size_t)sr * HIDDEN + cc * 32;
        float4 va = *reinterpret_cast<const float4*>(src + si * 4);
        float4 vb = *reinterpret_cast<const float4*>(src + 16 + si * 4);
        wb[sr][si*4+0] = va.x; wb[sr][si*4+1] = va.y;
        wb[sr][si*4+2] = va.z; wb[sr][si*4+3] = va.w;
        wb[sr][16+si*4+0] = vb.x; wb[sr][16+si*4+1] = vb.y;
        wb[sr][16+si*4+2] = vb.z; wb[sr][16+si*4+3] = vb.w;
        __syncthreads();
        #pragma unroll
        for (int cl = 0; cl < 32; ++cl) {
            float w = wb[t][cl];
            #pragma unroll
            for (int r = 0; r < 4; ++r)
                h[r] = fmaf(qh[rq * 4 + r][cc * 32 + cl], w, h[r]);
        }
        __syncthreads();
    }

    #pragma unroll
    for (int r = 0; r < 4; ++r) qh[rq * 4 + r][t] = fmaxf(h[r], 0.f);
    __syncthreads();

    float me[4];
    #pragma unroll
    for (int r = 0; r < 4; ++r) me[r] = b2[t];
    for (int cc = 0; cc < 8; ++cc) {
        const float* src = w2 + (size_t)sr * HIDDEN + cc * 32;
        float4 va = *reinterpret_cast<const float4*>(src + si * 4);
        float4 vb = *reinterpret_cast<const float4*>(src + 16 + si * 4);
        wb[sr][si*4+0] = va.x; wb[sr][si*4+1] = va.y;
        wb[sr][si*4+2] = va.z; wb[sr][si*4+3] = va.w;
        wb[sr][16+si*4+0] = vb.x; wb[sr][16+si*4+1] = vb.y;
        wb[sr][16+si*4+2] = vb.z; wb[sr][16+si*4+3] = vb.w;
        __syncthreads();
        #pragma unroll
        for (int cl = 0; cl < 32; ++cl) {
            float w = wb[t][cl];
            #pragma unroll
            for (int r = 0; r < 4; ++r)
                me[r] = fmaf(qh[rq * 4 + r][cc * 32 + cl], w, me[r]);
        }
        __syncthreads();
    }

    const int ks = t >> 5, g = (t >> 3) & 3, j = t & 7;
    #pragma unroll
    for (int r = 0; r < 4; ++r) {
        int row = rq * 4 + r;
        int q = mt * 16 + row;
        float v = (q < NQ) ? me[r] : 0.f;
        int lane = row + 16 * g;
        size_t addr = ((size_t)((b * MT + mt) * KSTEPS + ks)) * 512 + (size_t)lane * 8 + j;
        A_ws[addr] = (__bf16)v;
    }
}

// ---------------------------------------------------------------------------
// Kernel 2 v13: r13 ring pipeline + DEPTH-2 PREFETCH (vA/vB reg buffers).
// 256 blocks (1/CU), 512 thr / 8 waves, 152 KB LDS:
//   [A frags 104 KB (gload_lds, once)] [3 x 16 KB B half-panel ring]
// Loads for slot t issued at slot t-2 -> ~1.7 slots of latency cover before
// the counted-vmcnt retirement at their ds_write (r13 gave only the K-loop).
// Loop body = 2 slots (even uses vA-issue/vB-write; odd vB-issue/vA-write;
// static names per rule #20).
// Epilogue (odd slots): wave-private transpose in freed ring buffer
// (s+3)%3 = s0%3, NT f32x4 stores, zero block barriers. (r13, verified)
// B half-panel layout: elem (n,k): byte n*256 + (((k>>3) ^ (n&7))<<4) + (k&7)*2
// ---------------------------------------------------------------------------
__global__ __launch_bounds__(GT)
void mask_gemm(const float* __restrict__ mf,
               const __bf16* __restrict__ A_ws,
               float* __restrict__ out)
{
    extern __shared__ char smem[];
    char* Ar = smem;                   // A fragment region
    char* HB = smem + ABYTES;          // 3 half-panel buffers

    const int bid = blockIdx.x;
    const int b   = bid >> 6;                      // 64 blocks per batch
    const int px0 = (bid & 63) * (NTILE * NPB);    // 1024-px contiguous span
    const int tid = threadIdx.x;
    const int ln  = tid & 63, wv = tid >> 6;
    const int l15 = ln & 15,  lg = ln >> 4;
    const bool has2 = (wv + 8) < MT;
    const int sn = ln;                 // staging: n within tile
    const int su = wv;                 // staging: unit pair index

    const float*  mfB  = mf  + (size_t)b * HIDDEN * HW;
    const __bf16* Ab   = A_ws + (size_t)b * (MT * KSTEPS * 512);
    float*        outB = out + (size_t)b * NQ * HW;

    // ---- stage A panel into LDS (once): 13 frags per wave, lane-linear ----
    for (int fi = wv; fi < MT * KSTEPS; fi += 8)
        gload_lds16(Ab + (size_t)fi * 512 + (size_t)ln * 8,
                    Ar + fi * 1024 + ln * 16);

    float vA[16], vB[16];

    // issue loads for a slot (slot = 2*tile + half) into a reg buffer
    #define LOADV(dst, slot)                                                   \
        do {                                                                   \
            const int i_ = (slot) >> 1, h_ = (slot) & 1;                       \
            const float* src_ = mfB + (size_t)h_ * 128 * HW                    \
                                + px0 + i_ * NPB + sn;                         \
            _Pragma("unroll")                                                  \
            for (int c_ = 0; c_ < 2; ++c_)                                     \
                _Pragma("unroll")                                              \
                for (int j_ = 0; j_ < 8; ++j_)                                 \
                    dst[c_ * 8 + j_] =                                         \
                        src_[(size_t)((su * 2 + c_) * 8 + j_) * HW];           \
        } while (0)

    // cvt + swizzled ds_write of a reg buffer into ring buffer `base`
    #define DSWRITE(base, srcv)                                                \
        do {                                                                   \
            _Pragma("unroll")                                                  \
            for (int c_ = 0; c_ < 2; ++c_) {                                   \
                bf16x8 pk_;                                                    \
                _Pragma("unroll")                                              \
                for (int j_ = 0; j_ < 8; ++j_)                                 \
                    pk_[j_] = (__bf16)srcv[c_ * 8 + j_];                       \
                const int u_ = su * 2 + c_;                                    \
                *reinterpret_cast<bf16x8*>(                                    \
                    (base) + sn * 256 + ((u_ ^ (sn & 7)) << 4)) = pk_;         \
            }                                                                  \
        } while (0)

    // ---- prologue: slots 0 and 1 in flight; slot 0 into buf0 ----
    LOADV(vA, 0);
    LOADV(vB, 1);
    WAITVM0();                          // A gloads + vA + vB complete (once)
    DSWRITE(HB, vA);
    WAIT_LGKM0();
    hard_barrier();

    f32x4 acc[2][4];
    #pragma unroll
    for (int ii = 0; ii < 2; ++ii)
        #pragma unroll
        for (int f = 0; f < 4; ++f) acc[ii][f] = (f32x4){0.f, 0.f, 0.f, 0.f};

    // K-loop compute for one slot from ring buffer `bcur`, k-half `hh`
    #define COMPUTE(bcur, hh)                                                  \
        do {                                                                   \
            _Pragma("unroll")                                                  \
            for (int kk = 0; kk < 4; ++kk) {                                   \
                const int t_ = (hh) * 4 + kk;                                  \
                bf16x8 a0 = *reinterpret_cast<const bf16x8*>(                  \
                    Ar + (wv * KSTEPS + t_) * 1024 + ln * 16);                 \
                bf16x8 a1;                                                     \
                if (has2)                                                      \
                    a1 = *reinterpret_cast<const bf16x8*>(                     \
                        Ar + ((wv + 8) * KSTEPS + t_) * 1024 + ln * 16);       \
                _Pragma("unroll")                                              \
                for (int f = 0; f < 4; ++f) {                                  \
                    bf16x8 bf = *reinterpret_cast<const bf16x8*>(              \
                        (bcur) + (f * 16 + l15) * 256                          \
                        + (((kk * 4 + lg) ^ (l15 & 7)) << 4));                 \
                    acc[0][f] = __builtin_amdgcn_mfma_f32_16x16x32_bf16(       \
                        a0, bf, acc[0][f], 0, 0, 0);                           \
                    if (has2)                                                  \
                        acc[1][f] = __builtin_amdgcn_mfma_f32_16x16x32_bf16(   \
                            a1, bf, acc[1][f], 0, 0, 0);                       \
                }                                                              \
            }                                                                  \
        } while (0)

    // ---- main loop: 16 iterations x 2 slots ----
    for (int i = 0; i < NTILE; ++i) {
        const int s0 = 2 * i;

        // ===== even slot s0 (k-half 0) =====
        if (s0 + 2 < 2 * NTILE) {
            LOADV(vA, s0 + 2);
            __builtin_amdgcn_sched_barrier(0);
        }
        COMPUTE(HB + (s0 % 3) * HBB, 0);
        DSWRITE(HB + ((s0 + 1) % 3) * HBB, vB);   // slot s0+1 (loaded at s0-1)
        WAIT_LGKM0();
        hard_barrier();

        // ===== odd slot s0+1 (k-half 1) =====
        if (s0 + 3 < 2 * NTILE) {
            LOADV(vB, s0 + 3);
            __builtin_amdgcn_sched_barrier(0);
        }
        COMPUTE(HB + ((s0 + 1) % 3) * HBB, 1);
        if (s0 + 2 < 2 * NTILE)
            DSWRITE(HB + ((s0 + 2) % 3) * HBB, vA);  // slot s0+2 (loaded at s0)

        // epilogue: tile i complete -> wave-private transpose + NT stores.
        // Scratch = ring buffer (s0+3)%3 == s0%3: computed in the even slot
        // (reads drained at its barrier), next ds_written at slot s0+2 --
        // after this slot's ending barrier. Wave owns [wv*2048, +1024).
        {
            float* wscr = reinterpret_cast<float*>(
                HB + (s0 % 3) * HBB + wv * 2048);
            const int n0 = px0 + i * NPB;
            #pragma unroll
            for (int ii = 0; ii < 2; ++ii) {
                if (ii == 0 || has2) {
                    const int mt = wv + 8 * ii;
                    #pragma unroll
                    for (int sp = 0; sp < 4; ++sp) {
                        if (lg == sp) {
                            #pragma unroll
                            for (int f = 0; f < 4; ++f)
                                #pragma unroll
                                for (int r = 0; r < 4; ++r)
                                    wscr[r * 64 + f * 16 + l15] = acc[ii][f][r];
                        }
                        WAIT_LGKM0();            // wave-local: writes visible
                        {
                            const int row = ln >> 4, c4 = (ln & 15) << 2;
                            f32x4 vv = *reinterpret_cast<const f32x4*>(
                                wscr + row * 64 + c4);
                            const int q = mt * 16 + sp * 4 + row;
                            if (q < NQ)
                                __builtin_nontemporal_store(vv,
                                    reinterpret_cast<f32x4*>(
                                        outB + (size_t)q * HW + n0 + c4));
                        }
                        WAIT_LGKM0();            // reads done before next sp
                    }
                }
            }
            #pragma unroll
            for (int ii = 0; ii < 2; ++ii)
                #pragma unroll
                for (int f = 0; f < 4; ++f)
                    acc[ii][f] = (f32x4){0.f, 0.f, 0.f, 0.f};
        }

        WAIT_LGKM0();
        hard_barrier();
    }
    #undef LOADV
    #undef DSWRITE
    #undef COMPUTE
}

// ---------------------------------------------------------------------------
extern "C" void kernel_launch(void* const* d_in, const int* in_sizes, int n_in,
                              void* d_out, int out_size, void* d_ws, size_t ws_size,
                              hipStream_t stream)
{
    const float* queries = (const float*)d_in[0];
    const float* mf      = (const float*)d_in[1];
    const float* w1      = (const float*)d_in[2];
    const float* b1      = (const float*)d_in[3];
    const float* w2      = (const float*)d_in[4];
    const float* b2      = (const float*)d_in[5];
    float*  out  = (float*)d_out;
    __bf16* A_ws = (__bf16*)d_ws;   // 4*13*8*512*2 = 425,984 B

    (void)hipFuncSetAttribute((const void*)mask_gemm,
                              hipFuncAttributeMaxDynamicSharedMemorySize,
                              SMEM_TOTAL);

    hipLaunchKernelGGL(mlp_pack, dim3(NB * MT), dim3(1024), 0, stream,
                       queries, w1, b1, w2, b2, A_ws);
    hipLaunchKernelGGL(mask_gemm, dim3(NB * 64), dim3(GT), SMEM_TOTAL, stream,
                       mf, A_ws, out);
}